// Round 5
// baseline (693.014 us; speedup 1.0000x reference)
//
#include <hip/hip_runtime.h>
#include <hip/hip_bf16.h>

typedef __hip_bfloat16 bf16;
typedef unsigned short u16;
typedef unsigned int   u32;

#define NN     3000
#define EE     48000
#define NF     32
#define KEXC   1200
#define KDEN   10800.0f
#define NB     32
#define NT     512
#define NTH    (NB*NT)
#define S0     94            // slots/thread; NT*S0 = 48128 >= EE
#define DUMMYC 3070u         // gather target guaranteed 0.0
#define PADROW 3071u

// ---- workspace offsets (256-aligned). Rules:
//  * regions are written ONLY via agent-scope atomic stores (or RMW), then read
//    with plain cached loads strictly after the publishing barrier (write-once).
//  * [0, ZERO_BYTES) is zeroed by hipMemsetAsync before launch.
#define OFF_BAR  0u          // u32 barrier counter
#define OFF_TOT  256u        // 32 f32 (atomicAdd)
#define OFF_EXC  384u        // 32 f32 (atomicAdd)
#define OFF_DEG  512u        // 3000 int (atomicAdd)
#define ZERO_BYTES 12544u
#define OFF_CI   12544u      // 48000 u32 deduped cols (DUMMYC sentinel for dups)
#define OFF_Y1A  204800u     // conv1 y1 (3000x32 f32)
#define OFF_Y2A  589056u
#define OFF_Y1B  973312u     // conv2 y1
#define OFF_Y2B  1357568u
#define OFF_X1   1741824u
#define OFF_X2   2126080u

// ---- runtime dtype detection (validated rounds 2-4) ----
__device__ __forceinline__ bool scalar_is_bf16(const void* hp) {
    return ((const unsigned short*)hp)[0] != 0x0000;   // h==0.5
}
__device__ __forceinline__ bool tensor_is_bf16(const void* xp) {
    const unsigned short* u = (const unsigned short*)xp;
    int cnt = 0;
    for (int k = 0; k < 16; k++) {
        unsigned e = (u[2 * k] >> 7) & 0xFF;
        if (e >= 107 && e <= 147) cnt++;
    }
    return cnt >= 12;
}
__device__ __forceinline__ float ldv(const void* p, int i, bool b16) {
    return b16 ? __bfloat162float(((const bf16*)p)[i]) : ((const float*)p)[i];
}

// agent-scope (device-coherent) stores: land at the coherence point, no L2 flush needed
__device__ __forceinline__ void stf(float* p, float v) {
    __hip_atomic_store(p, v, __ATOMIC_RELAXED, __HIP_MEMORY_SCOPE_AGENT);
}
__device__ __forceinline__ void stu(u32* p, u32 v) {
    __hip_atomic_store(p, v, __ATOMIC_RELAXED, __HIP_MEMORY_SCOPE_AGENT);
}

// fence-free grid barrier: __syncthreads drains this block's stores (compiler
// emits s_waitcnt vmcnt(0) before s_barrier); counter is monotonic, target = 32*phase.
__device__ __forceinline__ void gbar(u32* bar, u32 target) {
    __syncthreads();
    if (threadIdx.x == 0) {
        __hip_atomic_fetch_add(bar, 1u, __ATOMIC_RELAXED, __HIP_MEMORY_SCOPE_AGENT);
        while (__hip_atomic_load(bar, __ATOMIC_RELAXED, __HIP_MEMORY_SCOPE_AGENT) < target)
            __builtin_amdgcn_s_sleep(1);
    }
    __syncthreads();
    __asm__ __volatile__("" ::: "memory");
}

__global__ void __launch_bounds__(NT, 2)
k_main(const void* xg, const int* ei, const void* hp, const void* ap,
       const void* Wr0, const void* Wa0, const void* Wb0,
       const void* Wr1, const void* Wa1, const void* Wb1,
       const void* pwp, const void* lwp, const void* lbp,
       char* ws, void* outp)
{
    const int t = threadIdx.x, blk = blockIdx.x, gid = blk * NT + t;

    u32*   bar  = (u32*)(ws + OFF_BAR);
    float* totf = (float*)(ws + OFF_TOT);
    float* excf = (float*)(ws + OFF_EXC);
    int*   deg  = (int*)(ws + OFF_DEG);
    u32*   ci   = (u32*)(ws + OFF_CI);
    float* y1a  = (float*)(ws + OFF_Y1A);
    float* y2a  = (float*)(ws + OFF_Y2A);
    float* y1b  = (float*)(ws + OFF_Y1B);
    float* y2b  = (float*)(ws + OFF_Y2B);
    float* x1   = (float*)(ws + OFF_X1);
    float* x2   = (float*)(ws + OFF_X2);

    __shared__ float s_y[3072];    // y col | scan ping | GEMM Wr | scores
    __shared__ float s_sys[3072];  // winv*y| scan pong | GEMM Wa | lcur/red
    __shared__ float s_b[3072];    // b col | u16 stage | GEMM Wb
    __shared__ float s_acc[3072];  // RP (exclusive rowptr ints) -> gather targets -> rnk
    __shared__ float s_w[3072];    // winv (persists)
    __shared__ int   s_fl[2];

    int* RPa = (int*)s_acc;

    // ========== P0: dtype detect (block-local) ==========
    if (t == 0) { s_fl[0] = tensor_is_bf16(xg) ? 1 : 0; s_fl[1] = scalar_is_bf16(hp) ? 1 : 0; }
    __syncthreads();
    const bool tb  = s_fl[0] != 0;
    const bool sbf = s_fl[1] != 0;
    const float hh = ldv(hp, 0, sbf);
    const float aa = ldv(ap, 0, sbf);

    // ========== P1: degree with duplicates (grid-strided atomics) ==========
    for (int e = gid; e < EE; e += NTH) atomicAdd(&deg[ei[e]], 1);
    gbar(bar, 1 * NB);

    // ========== P2: per-block scan -> RP, winv; row-sliced scatter + LDS dedup ==========
    {
        int* sA = (int*)s_y; int* sB = (int*)s_sys;
        for (int i = t; i < 3072; i += NT) sA[i] = (i < NN) ? deg[i] : 0;
        __syncthreads();
        for (int d = 1; d < 3072; d <<= 1) {
            for (int i = t; i < 3072; i += NT) sB[i] = sA[i] + ((i >= d) ? sA[i - d] : 0);
            __syncthreads();
            int* tmp = sA; sA = sB; sB = tmp;
        }
        if (t == 0) RPa[0] = 0;
        for (int i = t; i < NN; i += NT) RPa[i + 1] = sA[i];       // exclusive rowptr
        for (int i = t; i < 3072; i += NT)
            s_w[i] = (i < NN) ? (1.0f / (hh * ((float)deg[i] - aa))) : 0.0f;
        __syncthreads();

        const int r0 = blk * S0;
        const int r1 = (r0 + S0 < NN) ? (r0 + S0) : NN;
        const int base = RPa[r0];
        const int cnt  = RPa[r1] - base;
        int* lcur  = (int*)s_sys;                                  // 94 counters
        u16* stage = (u16*)s_b;                                    // <=4096 entries
        if (t < S0) lcur[t] = 0;
        __syncthreads();
        // scatter all edges belonging to my row slice into LDS stage
        for (int e = t; e < EE; e += NT) {
            int r = ei[e];
            if (r >= r0 && r < r1) {
                int pos = atomicAdd(&lcur[r - r0], 1);
                stage[(RPa[r] - base) + pos] = (u16)ei[EE + e];
            }
        }
        __syncthreads();
        // dedup in LDS, publish final cols (DUMMYC sentinel for dups)
        for (int ls = t; ls < cnt; ls += NT) {
            int g = base + ls;
            int lo = r0, hi = r1 - 1;
            while (lo < hi) { int mid = (lo + hi + 1) >> 1; if (RPa[mid] <= g) lo = mid; else hi = mid - 1; }
            int rsl = RPa[lo] - base;
            u16 c = stage[ls];
            bool dup = false;
            for (int ls2 = rsl; ls2 < ls; ls2++) dup |= (stage[ls2] == c);
            stu(&ci[g], dup ? DUMMYC : (u32)c);
        }
    }
    gbar(bar, 2 * NB);

    // ========== P3: pack slot schedule straight into registers ==========
    u32 sl[S0];
    {
        const int s0g = t * S0;
        int r = 0;
        if (s0g < EE) {
            int lo = 0, hi = NN - 1;
            while (lo < hi) { int mid = (lo + hi + 1) >> 1; if (RPa[mid] <= s0g) lo = mid; else hi = mid - 1; }
            r = lo;
        }
#pragma unroll
        for (int j = 0; j < S0; j++) {
            int s = s0g + j;
            u32 p;
            if (s < EE) {
                while (s >= RPa[r + 1]) r++;
                u32 c = ci[s];                                     // plain read (write-once region)
                int rs = RPa[r], re = RPa[r + 1];
                bool atEnd = (s == re - 1), atRange = (j == S0 - 1);
                bool flush = atEnd || atRange;
                bool part  = (rs < s0g) || !atEnd;
                p = c | ((u32)r << 12)
                  | (flush ? 0x40000000u : 0u)
                  | ((flush && part) ? 0x80000000u : 0u);
            } else {
                p = DUMMYC | (PADROW << 12) | ((j == S0 - 1) ? 0x40000000u : 0u);
            }
            sl[j] = p;
        }
    }
    __syncthreads();   // RPa (s_acc) done; chains may overwrite it

    // ========== convs ==========
    u32 phase = 2;
#pragma unroll 1
    for (int cv = 0; cv < 2; cv++) {
        const void* xin  = (cv == 0) ? xg : (const void*)x1;
        const bool  xtb  = (cv == 0) ? tb : false;
        float*      xout = (cv == 0) ? x1 : x2;
        float*      y1g  = (cv == 0) ? y1a : y1b;
        float*      y2g  = (cv == 0) ? y2a : y2b;
        const void* Wr   = (cv == 0) ? Wr0 : Wr1;
        const void* Wa   = (cv == 0) ? Wa0 : Wa1;
        const void* Wb   = (cv == 0) ? Wb0 : Wb1;

        // column init: f = blk; also zero gather targets
#pragma unroll
        for (int k = 0; k < 6; k++) {
            int i = t + k * NT;
            float v = (i < NN) ? ldv(xin, i * NF + blk, xtb) : 0.0f;
            s_y[i] = v; s_sys[i] = s_w[i] * v; s_acc[i] = 0.0f;
        }
        __syncthreads();

#pragma unroll 1
        for (int ord = 0; ord < 2; ord++) {
#pragma unroll 1
            for (int step = 0; step < 6; step++) {     // 0 = b-step, 1..5 = Jacobi
                const float* src = (step == 0) ? s_y : s_sys;
                float acc = 0.f;
#pragma unroll
                for (int s = 0; s < S0; s++) {
                    u32 p = sl[s];
                    acc += src[p & 0xFFFu];
                    if (p & 0x40000000u) {
                        int r = (int)((p >> 12) & 0xFFFu);
                        if (p & 0x80000000u) atomicAdd(&s_acc[r], acc);
                        else                 s_acc[r] = acc;
                        acc = 0.f;
                    }
                }
                __syncthreads();
                if (step == 0) {
#pragma unroll
                    for (int k = 0; k < 6; k++) {
                        int i = t + k * NT;
                        float a = s_acc[i]; s_acc[i] = 0.f;
                        if (i < NN) {
                            float nb = s_y[i] - hh * s_w[i] * a;   // y - (1/dvals)*sum
                            s_b[i] = nb; s_y[i] = nb; s_sys[i] = s_w[i] * nb;
                        }
                    }
                } else {
#pragma unroll
                    for (int k = 0; k < 6; k++) {
                        int i = t + k * NT;
                        float a = s_acc[i]; s_acc[i] = 0.f;
                        if (i < NN) {
                            float y = s_b[i] + a;                  // b + J*y
                            s_y[i] = y; s_sys[i] = s_w[i] * y;
                        }
                    }
                }
                __syncthreads();
            }
            float* yg = (ord == 0) ? y1g : y2g;
#pragma unroll
            for (int k = 0; k < 6; k++) {
                int i = t + k * NT;
                if (i < NN) stf(&yg[i * NF + blk], s_y[i]);
            }
        }
        gbar(bar, (++phase) * NB);   // y1g/y2g complete grid-wide

        // GEMM: xout = relu(xin@Wr^T + 2 y1@Wa^T + 2 y2@Wb^T); W staged in LDS
        for (int i2 = t; i2 < 1024; i2 += NT) {
            s_y[i2]   = ldv(Wr, i2, tb);
            s_sys[i2] = ldv(Wa, i2, tb);
            s_b[i2]   = ldv(Wb, i2, tb);
        }
        __syncthreads();
        for (int w = gid; w < NN * 8; w += NTH) {
            int i = w >> 3, q = (w & 7) * 4;
            const float* y1r = y1g + i * NF;
            const float* y2r = y2g + i * NF;
            float a0 = 0.f, a1 = 0.f, a2 = 0.f, a3 = 0.f;
#pragma unroll
            for (int f = 0; f < NF; f++) {
                float xv = ldv(xin, i * NF + f, xtb);
                float v1 = 2.0f * y1r[f], v2 = 2.0f * y2r[f];
                a0 += xv * s_y[(q + 0) * 32 + f] + v1 * s_sys[(q + 0) * 32 + f] + v2 * s_b[(q + 0) * 32 + f];
                a1 += xv * s_y[(q + 1) * 32 + f] + v1 * s_sys[(q + 1) * 32 + f] + v2 * s_b[(q + 1) * 32 + f];
                a2 += xv * s_y[(q + 2) * 32 + f] + v1 * s_sys[(q + 2) * 32 + f] + v2 * s_b[(q + 2) * 32 + f];
                a3 += xv * s_y[(q + 3) * 32 + f] + v1 * s_sys[(q + 3) * 32 + f] + v2 * s_b[(q + 3) * 32 + f];
            }
            stf(&xout[i * NF + q + 0], fmaxf(a0, 0.f));
            stf(&xout[i * NF + q + 1], fmaxf(a1, 0.f));
            stf(&xout[i * NF + q + 2], fmaxf(a2, 0.f));
            stf(&xout[i * NF + q + 3], fmaxf(a3, 0.f));
        }
        gbar(bar, (++phase) * NB);   // x1 / x2 complete
    }

    // ========== pooling: per-block scores + exact top_k rank counting ==========
    {
        float nrm2 = 0.f;
        for (int f = 0; f < NF; f++) { float v = ldv(pwp, f, tb); nrm2 += v * v; }
        const float nrm = sqrtf(nrm2);
        for (int i = t; i < NN; i += NT) {          // all 3000 scores, block-locally
            const float* xr = x2 + i * NF;
            float d = 0.f;
            for (int f = 0; f < NF; f++) d += xr[f] * ldv(pwp, f, tb);
            s_y[i] = tanhf(d / nrm);
        }
        int* rnk = (int*)s_acc;
        if (t < S0) rnk[t] = 0;
        __syncthreads();

        const int j0 = blk * S0;
        const int j1 = (j0 + S0 < NN) ? (j0 + S0) : NN;
        // rank of my rows among all 3000 (key = (score asc, index desc))
        for (int u = t; u < S0 * 5; u += NT) {
            int lr = u / 5, i = j0 + lr;
            if (i < j1) {
                float si = s_y[i];
                if (si < 0.f) {
                    int seg = (u % 5) * 600;
                    int cnt = 0;
                    for (int j = seg; j < seg + 600 && j < NN; j++) {
                        float sj = s_y[j];
                        cnt += (sj < si) || ((sj == si) && (j > i));
                    }
                    if (cnt) atomicAdd(&rnk[lr], cnt);
                }
            }
        }
        __syncthreads();

        // tot/exc partials over my row slice
        float* red = s_sys;
        int f = t & 31, rl = t >> 5;
        float at = 0.f, ae = 0.f;
        for (int lr = rl; lr < S0; lr += 16) {
            int i = j0 + lr;
            if (i < j1) {
                float si = s_y[i];
                float term = x2[i * NF + f] * si;
                at += term;
                if (si < 0.f && rnk[lr] < KEXC) ae += term;
            }
        }
        red[t] = at; __syncthreads();
        for (int s = 256; s >= 32; s >>= 1) { if (t < s) red[t] += red[t + s]; __syncthreads(); }
        if (t < 32) atomicAdd(&totf[t], red[t]);
        __syncthreads();
        red[t] = ae; __syncthreads();
        for (int s = 256; s >= 32; s >>= 1) { if (t < s) red[t] += red[t + s]; __syncthreads(); }
        if (t < 32) atomicAdd(&excf[t], red[t]);
    }
    gbar(bar, 7 * NB);

    // ========== final linear (block 0) ==========
    if (blk == 0 && t < 8) {
        float o = ldv(lbp, t, tb);
        for (int f = 0; f < NF; f++)
            o += ((totf[f] - excf[f]) / KDEN) * ldv(lwp, t * 32 + f, tb);
        if (tb) ((bf16*)outp)[t] = __float2bfloat16(o);
        else    ((float*)outp)[t] = o;
    }
}

extern "C" void kernel_launch(void* const* d_in, const int* in_sizes, int n_in,
                              void* d_out, int out_size, void* d_ws, size_t ws_size,
                              hipStream_t stream) {
    const void* x   = d_in[0];
    const int*  ei  = (const int*)d_in[1];
    const void* hp  = d_in[2];
    const void* ap  = d_in[3];
    const void* Wr0 = d_in[4];
    const void* Wa0 = d_in[5];
    const void* Wb0 = d_in[6];
    const void* Wr1 = d_in[7];
    const void* Wa1 = d_in[8];
    const void* Wb1 = d_in[9];
    const void* pw  = d_in[10];
    const void* lw  = d_in[11];
    const void* lb  = d_in[12];
    char* ws   = (char*)d_ws;
    void* outp = d_out;

    hipMemsetAsync(ws, 0, ZERO_BYTES, stream);

    void* args[15] = {
        (void*)&x, (void*)&ei, (void*)&hp, (void*)&ap,
        (void*)&Wr0, (void*)&Wa0, (void*)&Wb0,
        (void*)&Wr1, (void*)&Wa1, (void*)&Wb1,
        (void*)&pw, (void*)&lw, (void*)&lb,
        (void*)&ws, (void*)&outp
    };
    hipLaunchCooperativeKernel((const void*)k_main, dim3(NB), dim3(NT), args, 0, stream);
}

// Round 6
// 389.469 us; speedup vs baseline: 1.7794x; 1.7794x over previous
//
#include <hip/hip_runtime.h>
#include <hip/hip_bf16.h>

typedef __hip_bfloat16 bf16;
typedef unsigned short u16;
typedef unsigned int   u32;

#define NN     3000
#define EE     48000
#define NF     32
#define KEXC   1200
#define KDEN   10800.0f
#define CT     1024          // chains threads/block
#define CS     47            // slots/thread: 1024*47 = 48128
#define SLOTS  48128
#define DUMMYC 3070u         // gather target guaranteed 0.0f
#define PADROW 3071u

// ---- workspace offsets (zero region first; memset once before launch) ----
#define OFF_DEG   0u         // 3000 int  (atomicAdd)
#define OFF_TOT   12032u     // 32 f32    (atomicAdd)
#define OFF_EXC   12160u     // 32 f32    (atomicAdd)
#define ZERO_BYTES 12288u
#define OFF_SLOT  12288u     // 48128 u32 packed slots, layout [j][t]
#define OFF_WINV  204800u    // 3000 f32
#define OFF_Y1    217088u    // 3000*32 f32
#define OFF_Y2    601088u
#define OFF_X1    985088u
#define OFF_X2    1369088u

// ---- runtime dtype detection (validated rounds 2-5) ----
__device__ __forceinline__ bool scalar_is_bf16(const void* hp) {
    return ((const unsigned short*)hp)[0] != 0x0000;   // h==0.5
}
__device__ __forceinline__ bool tensor_is_bf16(const void* xp) {
    const unsigned short* u = (const unsigned short*)xp;
    int cnt = 0;
    for (int k = 0; k < 16; k++) {
        unsigned e = (u[2 * k] >> 7) & 0xFF;
        if (e >= 107 && e <= 147) cnt++;
    }
    return cnt >= 12;
}
__device__ __forceinline__ float ldv(const void* p, int i, bool b16) {
    return b16 ? __bfloat162float(((const bf16*)p)[i]) : ((const float*)p)[i];
}

// ================= 1: degree (with duplicates) =================
__global__ void k_deg(const int* __restrict__ ei, int* __restrict__ deg) {
    int e = blockIdx.x * blockDim.x + threadIdx.x;
    if (e < EE) atomicAdd(&deg[ei[e]], 1);
}

// ================= 2: CSR + dedup + packed slot schedule =================
__global__ void __launch_bounds__(512)
k_csr(const int* __restrict__ ei, const int* __restrict__ deg,
      const void* hp, const void* ap,
      float* __restrict__ winv, u32* __restrict__ slotT) {
    __shared__ int sA[3072], sB[3072], RP[3072];
    __shared__ u16 stage[4096], stage2[4096];
    __shared__ int lcur[96];
    __shared__ int s_fl;
    const int t = threadIdx.x, blk = blockIdx.x;
    const int NT = 512;

    if (t == 0) s_fl = scalar_is_bf16(hp) ? 1 : 0;
    __syncthreads();
    const bool sbf = s_fl != 0;
    const float hh = ldv(hp, 0, sbf), aa = ldv(ap, 0, sbf);

    // inclusive scan of deg
    for (int i = t; i < 3072; i += NT) sA[i] = (i < NN) ? deg[i] : 0;
    __syncthreads();
    int* src = sA; int* dst = sB;
    for (int d = 1; d < 3072; d <<= 1) {
        for (int i = t; i < 3072; i += NT) dst[i] = src[i] + ((i >= d) ? src[i - d] : 0);
        __syncthreads();
        int* tmp = src; src = dst; dst = tmp;
    }
    for (int i = t; i < 3072; i += NT) RP[i] = (i == 0) ? 0 : ((i <= NN) ? src[i - 1] : EE);
    __syncthreads();

    // winv (only block 0 writes globals shared by all)
    if (blk == 0)
        for (int i = t; i < NN; i += NT)
            winv[i] = 1.0f / (hh * ((float)deg[i] - aa));

    // my row slice
    const int r0 = blk * 94;
    const int r1 = (r0 + 94 < NN) ? (r0 + 94) : NN;
    const int base = RP[r0];
    const int cnt  = RP[r1] - base;
    if (t < 96) lcur[t] = 0;
    __syncthreads();
    // scatter my rows' edges into stage
    for (int e = t; e < EE; e += NT) {
        int r = ei[e];
        if (r >= r0 && r < r1) {
            int pos = atomicAdd(&lcur[r - r0], 1);
            stage[(RP[r] - base) + pos] = (u16)ei[EE + e];
        }
    }
    __syncthreads();
    // dedup: keep first occurrence per row, dups -> DUMMYC
    for (int ls = t; ls < cnt; ls += NT) {
        int g = base + ls;
        int lo = r0, hi = r1 - 1;
        while (lo < hi) { int mid = (lo + hi + 1) >> 1; if (RP[mid] <= g) lo = mid; else hi = mid - 1; }
        int rsl = RP[lo] - base;
        u16 c = stage[ls];
        bool dup = false;
        for (int ls2 = rsl; ls2 < ls; ls2++) dup |= (stage[ls2] == c);
        stage2[ls] = dup ? (u16)DUMMYC : c;
    }
    __syncthreads();
    // pack slot words for my slots; layout slotT[j*CT + tc] for chains coalescing
    for (int ls = t; ls < cnt; ls += NT) {
        int s = base + ls;
        int lo = r0, hi = r1 - 1;
        while (lo < hi) { int mid = (lo + hi + 1) >> 1; if (RP[mid] <= s) lo = mid; else hi = mid - 1; }
        int r = lo;
        int rs = RP[r], re = RP[r + 1];
        int tc = s / CS, j = s % CS;
        int rangeStart = tc * CS;
        bool atEnd = (s == re - 1), atRange = (j == CS - 1);
        bool flush = atEnd || atRange;
        bool part  = (rs < rangeStart) || !atEnd;
        u32 p = (u32)stage2[ls] | ((u32)r << 12)
              | (flush ? 0x40000000u : 0u)
              | ((flush && part) ? 0x80000000u : 0u);
        slotT[j * CT + tc] = p;
    }
    // padding slots
    if (blk == gridDim.x - 1) {
        for (int s = EE + t; s < SLOTS; s += NT) {
            int tc = s / CS, j = s % CS;
            slotT[j * CT + tc] = DUMMYC | (PADROW << 12) | ((j == CS - 1) ? 0x40000000u : 0u);
        }
    }
}

// ================= 3: Cayley chains (one feature column per block) =================
__global__ void __launch_bounds__(CT, 1)
k_chains(const void* __restrict__ xin, int detect, const void* hp,
         const u32* __restrict__ slotT, const float* __restrict__ winv,
         float* __restrict__ y1g, float* __restrict__ y2g) {
    __shared__ float s_y[3072], s_sys[3072], s_b[3072], s_acc[3072], s_w[3072];
    __shared__ int s_fl[2];
    const int t = threadIdx.x, blk = blockIdx.x;

    if (t == 0) {
        s_fl[0] = (detect && tensor_is_bf16(xin)) ? 1 : 0;
        s_fl[1] = scalar_is_bf16(hp) ? 1 : 0;
    }
    __syncthreads();
    const bool xtb = s_fl[0] != 0;
    const float hh = ldv(hp, 0, s_fl[1] != 0);

    u32 sl[CS];
#pragma unroll
    for (int j = 0; j < CS; j++) sl[j] = slotT[j * CT + t];

#pragma unroll
    for (int k = 0; k < 3; k++) {
        int i = t + k * CT;
        float v = (i < NN) ? ldv(xin, i * NF + blk, xtb) : 0.0f;
        float w = (i < NN) ? winv[i] : 0.0f;
        s_w[i] = w; s_y[i] = v; s_sys[i] = w * v; s_acc[i] = 0.0f;
    }
    __syncthreads();

#pragma unroll 1
    for (int ord = 0; ord < 2; ord++) {
#pragma unroll 1
        for (int step = 0; step < 6; step++) {        // 0 = b-step, 1..5 = Jacobi
            const float* src = (step == 0) ? s_y : s_sys;
            float acc = 0.f;
#pragma unroll
            for (int s = 0; s < CS; s++) {
                u32 p = sl[s];
                acc += src[p & 0xFFFu];
                if (p & 0x40000000u) {
                    int r = (int)((p >> 12) & 0xFFFu);
                    if (p & 0x80000000u) atomicAdd(&s_acc[r], acc);
                    else                 s_acc[r] = acc;
                    acc = 0.f;
                }
            }
            __syncthreads();
            if (step == 0) {
#pragma unroll
                for (int k = 0; k < 3; k++) {
                    int i = t + k * CT;
                    float a = s_acc[i]; s_acc[i] = 0.f;
                    if (i < NN) {
                        float nb = s_y[i] - hh * s_w[i] * a;      // y - (1/dvals)*sum
                        s_b[i] = nb; s_y[i] = nb; s_sys[i] = s_w[i] * nb;
                    }
                }
            } else {
#pragma unroll
                for (int k = 0; k < 3; k++) {
                    int i = t + k * CT;
                    float a = s_acc[i]; s_acc[i] = 0.f;
                    if (i < NN) {
                        float y = s_b[i] + a;                     // b + J*y
                        s_y[i] = y; s_sys[i] = s_w[i] * y;
                    }
                }
            }
            __syncthreads();
        }
        float* yg = (ord == 0) ? y1g : y2g;
#pragma unroll
        for (int k = 0; k < 3; k++) {
            int i = t + k * CT;
            if (i < NN) yg[i * NF + blk] = s_y[i];
        }
    }
}

// ================= 4: GEMM epilogue =================
__global__ void __launch_bounds__(256)
k_gemm(const void* __restrict__ xin, int detect,
       const void* __restrict__ Wr, const void* __restrict__ Wa, const void* __restrict__ Wb,
       const float* __restrict__ y1g, const float* __restrict__ y2g,
       float* __restrict__ xout) {
    __shared__ float sWr[1024], sWa[1024], sWb[1024];
    __shared__ int s_fl[2];
    const int t = threadIdx.x;
    if (t == 0) {
        s_fl[0] = (detect && tensor_is_bf16(xin)) ? 1 : 0;
        s_fl[1] = tensor_is_bf16(Wr) ? 1 : 0;    // weights follow dataset dtype
    }
    __syncthreads();
    const bool xtb = s_fl[0] != 0, wtb = s_fl[1] != 0;
    for (int i = t; i < 1024; i += 256) {
        sWr[i] = ldv(Wr, i, wtb);
        sWa[i] = ldv(Wa, i, wtb);
        sWb[i] = ldv(Wb, i, wtb);
    }
    __syncthreads();
    int w = blockIdx.x * 256 + t;
    if (w >= NN * 8) return;
    int i = w >> 3, q = (w & 7) * 4;
    const float* y1r = y1g + i * NF;
    const float* y2r = y2g + i * NF;
    float a0 = 0.f, a1 = 0.f, a2 = 0.f, a3 = 0.f;
#pragma unroll
    for (int f = 0; f < NF; f++) {
        float xv = ldv(xin, i * NF + f, xtb);
        float v1 = 2.0f * y1r[f], v2 = 2.0f * y2r[f];
        a0 += xv * sWr[(q + 0) * 32 + f] + v1 * sWa[(q + 0) * 32 + f] + v2 * sWb[(q + 0) * 32 + f];
        a1 += xv * sWr[(q + 1) * 32 + f] + v1 * sWa[(q + 1) * 32 + f] + v2 * sWb[(q + 1) * 32 + f];
        a2 += xv * sWr[(q + 2) * 32 + f] + v1 * sWa[(q + 2) * 32 + f] + v2 * sWb[(q + 2) * 32 + f];
        a3 += xv * sWr[(q + 3) * 32 + f] + v1 * sWa[(q + 3) * 32 + f] + v2 * sWb[(q + 3) * 32 + f];
    }
    float4 r;
    r.x = fmaxf(a0, 0.f); r.y = fmaxf(a1, 0.f); r.z = fmaxf(a2, 0.f); r.w = fmaxf(a3, 0.f);
    *(float4*)(xout + i * NF + q) = r;
}

// ================= 5: pooling (scores + exact top_k rank counting) =================
__global__ void __launch_bounds__(512)
k_pool(const float* __restrict__ x2, const void* __restrict__ pwp,
       float* __restrict__ totf, float* __restrict__ excf) {
    __shared__ float s_s[3072];
    __shared__ float red[512];
    __shared__ int rnk[96];
    __shared__ int s_fl;
    const int t = threadIdx.x, blk = blockIdx.x;
    const int NT = 512;

    if (t == 0) s_fl = tensor_is_bf16(pwp) ? 1 : 0;
    __syncthreads();
    const bool tb = s_fl != 0;
    float pw[32];
    float nrm2 = 0.f;
#pragma unroll
    for (int f = 0; f < NF; f++) { pw[f] = ldv(pwp, f, tb); nrm2 += pw[f] * pw[f]; }
    const float nrm = sqrtf(nrm2);

    for (int i = t; i < 3072; i += NT) {
        float d = 0.f;
        if (i < NN) {
            const float* xr = x2 + i * NF;
#pragma unroll
            for (int f = 0; f < NF; f++) d += xr[f] * pw[f];
            s_s[i] = tanhf(d / nrm);
        } else s_s[i] = 0.f;
    }
    if (t < 96) rnk[t] = 0;
    __syncthreads();

    const int j0 = blk * 94;
    const int j1 = (j0 + 94 < NN) ? (j0 + 94) : NN;
    // rank of my rows among all 3000 (key = (score asc, index desc)); only negatives matter
    for (int u = t; u < 94 * 5; u += NT) {
        int lr = u / 5, i = j0 + lr;
        if (i < j1) {
            float si = s_s[i];
            if (si < 0.f) {
                int seg = (u % 5) * 600;
                int cnt = 0;
                for (int j = seg; j < seg + 600 && j < NN; j++) {
                    float sj = s_s[j];
                    cnt += (sj < si) || ((sj == si) && (j > i));
                }
                if (cnt) atomicAdd(&rnk[lr], cnt);
            }
        }
    }
    __syncthreads();

    int f = t & 31, rl = t >> 5;
    float at = 0.f, ae = 0.f;
    for (int lr = rl; lr < 94; lr += 16) {
        int i = j0 + lr;
        if (i < j1) {
            float si = s_s[i];
            float term = x2[i * NF + f] * si;
            at += term;
            if (si < 0.f && rnk[lr] < KEXC) ae += term;
        }
    }
    red[t] = at; __syncthreads();
    for (int s = 256; s >= 32; s >>= 1) { if (t < s) red[t] += red[t + s]; __syncthreads(); }
    if (t < 32) atomicAdd(&totf[t], red[t]);
    __syncthreads();
    red[t] = ae; __syncthreads();
    for (int s = 256; s >= 32; s >>= 1) { if (t < s) red[t] += red[t + s]; __syncthreads(); }
    if (t < 32) atomicAdd(&excf[t], red[t]);
}

// ================= 6: final linear =================
__global__ void k_final(const void* __restrict__ lwp, const void* __restrict__ lbp,
                        const float* __restrict__ totf, const float* __restrict__ excf,
                        void* __restrict__ outp) {
    const int t = threadIdx.x;
    __shared__ int s_fl;
    if (t == 0) s_fl = tensor_is_bf16(lwp) ? 1 : 0;
    __syncthreads();
    const bool tb = s_fl != 0;
    if (t < 8) {
        float o = ldv(lbp, t, tb);
        for (int f = 0; f < NF; f++)
            o += ((totf[f] - excf[f]) / KDEN) * ldv(lwp, t * 32 + f, tb);
        if (tb) ((bf16*)outp)[t] = __float2bfloat16(o);
        else    ((float*)outp)[t] = o;
    }
}

extern "C" void kernel_launch(void* const* d_in, const int* in_sizes, int n_in,
                              void* d_out, int out_size, void* d_ws, size_t ws_size,
                              hipStream_t stream) {
    const void* x   = d_in[0];
    const int*  ei  = (const int*)d_in[1];
    const void* hp  = d_in[2];
    const void* ap  = d_in[3];
    const void* Wr0 = d_in[4];
    const void* Wa0 = d_in[5];
    const void* Wb0 = d_in[6];
    const void* Wr1 = d_in[7];
    const void* Wa1 = d_in[8];
    const void* Wb1 = d_in[9];
    const void* pw  = d_in[10];
    const void* lw  = d_in[11];
    const void* lb  = d_in[12];
    char* ws = (char*)d_ws;

    int*   deg   = (int*)(ws + OFF_DEG);
    float* totf  = (float*)(ws + OFF_TOT);
    float* excf  = (float*)(ws + OFF_EXC);
    u32*   slotT = (u32*)(ws + OFF_SLOT);
    float* winv  = (float*)(ws + OFF_WINV);
    float* y1g   = (float*)(ws + OFF_Y1);
    float* y2g   = (float*)(ws + OFF_Y2);
    float* x1    = (float*)(ws + OFF_X1);
    float* x2    = (float*)(ws + OFF_X2);

    hipMemsetAsync(ws, 0, ZERO_BYTES, stream);
    k_deg   <<<dim3((EE + 255) / 256), dim3(256), 0, stream>>>(ei, deg);
    k_csr   <<<dim3(32),  dim3(512),  0, stream>>>(ei, deg, hp, ap, winv, slotT);
    k_chains<<<dim3(32),  dim3(CT),   0, stream>>>(x, 1, hp, slotT, winv, y1g, y2g);
    k_gemm  <<<dim3(94),  dim3(256),  0, stream>>>(x, 1, Wr0, Wa0, Wb0, y1g, y2g, x1);
    k_chains<<<dim3(32),  dim3(CT),   0, stream>>>(x1, 0, hp, slotT, winv, y1g, y2g);
    k_gemm  <<<dim3(94),  dim3(256),  0, stream>>>(x1, 0, Wr1, Wa1, Wb1, y1g, y2g, x2);
    k_pool  <<<dim3(32),  dim3(512),  0, stream>>>(x2, pw, totf, excf);
    k_final <<<dim3(1),   dim3(64),   0, stream>>>(lw, lb, totf, excf, d_out);
}